// Round 7
// baseline (345.527 us; speedup 1.0000x reference)
//
#include <hip/hip_runtime.h>
#include <hip/hip_bf16.h>

#define HH 100
#define WW 352
#define NB 2
#define LL 5
#define NN 10
#define CCH 64
#define HW (HH*WW)
#define KTOP (HW/4)
#define HP (HH+6)
#define WP 390   // padded row length, covers conv reads

typedef __bf16 bf16x8 __attribute__((ext_vector_type(8)));
typedef float f32x4 __attribute__((ext_vector_type(4)));
typedef int int4v __attribute__((ext_vector_type(4)));

// ws layout (bytes), 16B aligned
#define WS_CONF  0u
#define WS_TAU   1408000u
#define WS_WTP   1408064u
#define WS_PAD   1809472u
#define WS_XT    12392512u
#define PAD_BYTES ((size_t)NB*HP*WP*CCH*2)      // 10,583,040

__device__ __forceinline__ void load_theta(const float* __restrict__ ptm, int b, int l, float th[6]) {
#pragma clang fp contract(off)
  const float* tb = ptm + ((b*LL + 0)*LL + l)*16;  // pairwise_t_matrix[b,0,l,:,:]
  th[0] = tb[0] * 1.0f;
  th[1] = tb[1] * (float)(100.0/352.0);
  th[2] = tb[3] * (float)(2.0/(2.0*0.4*352.0));
  th[3] = tb[4] * (float)(352.0/100.0);
  th[4] = tb[5] * 1.0f;
  th[5] = tb[7] * (float)(2.0/(2.0*0.4*100.0));
}

// --- Kernel 1: conf_w = bilinear-warp of sigmoid(max(psm[n,0],psm[n,1])) ---
__global__ void conf_warp_kernel(const float* __restrict__ psm,
                                 const float* __restrict__ ptm,
                                 float* __restrict__ conf_w) {
#pragma clang fp contract(off)
  int w = blockIdx.x * 128 + threadIdx.x;
  int h = blockIdx.y;
  int n = blockIdx.z;
  if (w >= WW) return;
  int b = n / LL, l = n % LL;
  float th[6];
  load_theta(ptm, b, l, th);
  float gy = ((float)h + 0.5f) * (float)(2.0/100.0) - 1.0f;
  float gx = ((float)w + 0.5f) * (float)(2.0/352.0) - 1.0f;
  float sx = th[0]*gx + th[1]*gy + th[2];
  float sy = th[3]*gx + th[4]*gy + th[5];
  float px = (sx + 1.0f) * ((float)WW * 0.5f) - 0.5f;
  float py = (sy + 1.0f) * ((float)HH * 0.5f) - 0.5f;
  float x0 = floorf(px), y0 = floorf(py);
  float wx1 = px - x0, wx0 = 1.0f - wx1;
  float wy1 = py - y0, wy0 = 1.0f - wy1;
  const float* p0 = psm + (size_t)(n*2 + 0)*HW;
  const float* p1 = psm + (size_t)(n*2 + 1)*HW;
  float yy[2] = {y0, y0 + 1.0f};
  float xx[2] = {x0, x0 + 1.0f};
  float wgt[2][2] = {{wy0*wx0, wy0*wx1}, {wy1*wx0, wy1*wx1}};
  float out = 0.0f;
  for (int iy = 0; iy < 2; ++iy) {
    for (int ix = 0; ix < 2; ++ix) {
      float yv = yy[iy], xv = xx[ix];
      float yc = fminf(fmaxf(yv, 0.0f), (float)(HH-1));
      float xc = fminf(fmaxf(xv, 0.0f), (float)(WW-1));
      int yi = (int)yc, xi = (int)xc;
      int idx = yi*WW + xi;
      float m = fmaxf(p0[idx], p1[idx]);
      float v = 1.0f / (1.0f + expf(-m));
      bool valid = (yv >= 0.0f) && (yv <= (float)(HH-1)) && (xv >= 0.0f) && (xv <= (float)(WW-1));
      out += (valid ? v : 0.0f) * wgt[iy][ix];
    }
  }
  conf_w[(size_t)n*HW + h*WW + w] = out;
}

// inclusive block scan over 256 threads (thread order = descending bins)
__device__ __forceinline__ unsigned int scan_incl(unsigned int v, int lane, int wid,
                                                  volatile unsigned int* wsum) {
  unsigned int inc = v;
  for (int off = 1; off < 64; off <<= 1) {
    unsigned int o = __shfl_up(inc, off);
    if (lane >= off) inc += o;
  }
  if (lane == 63) wsum[wid] = inc;
  __syncthreads();
  unsigned int wadd = 0;
  for (int w2 = 0; w2 < wid; ++w2) wadd += wsum[w2];
  return inc + wadd;
}

// --- Kernel 2: exact K-th largest per image, 3-round (14/14/4-bit) LDS radix select ---
__global__ __launch_bounds__(256) void topk_kernel(const float* __restrict__ conf_w,
                                                   float* __restrict__ tau) {
  __shared__ unsigned int hist[16384];
  __shared__ unsigned int wsum[4];
  __shared__ unsigned int s_pref, s_mask, s_k;
  int n = blockIdx.x;
  int tid = threadIdx.x, lane = tid & 63, wid = tid >> 6;
  const float4* src = (const float4*)(conf_w + (size_t)n*HW);
  if (tid == 0) { s_pref = 0u; s_mask = 0u; s_k = KTOP; }
  __syncthreads();
  const int shifts[3] = {18, 4, 0};
  const int widths[3] = {14, 14, 4};
  for (int r = 0; r < 3; ++r) {
    int shift = shifts[r];
    int nbins = 1 << widths[r];
    unsigned int fmask = (unsigned int)(nbins - 1);
    for (int i = tid; i < nbins; i += 256) hist[i] = 0u;
    __syncthreads();
    unsigned int maskhi = s_mask, pref = s_pref, k = s_k;
    for (int i = tid; i < HW/4; i += 256) {
      float4 v = src[i];
      unsigned int u0 = __float_as_uint(v.x);
      unsigned int u1 = __float_as_uint(v.y);
      unsigned int u2 = __float_as_uint(v.z);
      unsigned int u3 = __float_as_uint(v.w);
      if ((u0 & maskhi) == pref) atomicAdd(&hist[(u0 >> shift) & fmask], 1u);
      if ((u1 & maskhi) == pref) atomicAdd(&hist[(u1 >> shift) & fmask], 1u);
      if ((u2 & maskhi) == pref) atomicAdd(&hist[(u2 >> shift) & fmask], 1u);
      if ((u3 & maskhi) == pref) atomicAdd(&hist[(u3 >> shift) & fmask], 1u);
    }
    __syncthreads();
    int C = nbins >> 8; if (C == 0) C = 1;
    int active = (C * 256 > nbins) ? nbins : 256;
    int top = nbins - 1 - tid*C;
    unsigned int csum = 0u;
    if (tid < active)
      for (int i = 0; i < C; ++i) csum += hist[top - i];
    unsigned int incl = scan_incl(csum, lane, wid, wsum);
    unsigned int excl = incl - csum;
    if (tid < active && excl < k && incl >= k) {
      unsigned int run = excl;
      for (int i = 0; i < C; ++i) {
        unsigned int c = hist[top - i];
        if (run + c >= k) {
          unsigned int bin = (unsigned int)(top - i);
          s_pref = pref | (bin << shift);
          s_mask = maskhi | (fmask << shift);
          s_k = k - run;
          break;
        }
        run += c;
      }
    }
    __syncthreads();
  }
  if (tid == 0) tau[n] = __uint_as_float(s_pref);
}

// --- Kernel 3: weights fuse_w[k][c][dy][dx] -> wtp[(dy*7+dx)*64 + k][c] bf16 ---
__global__ void pack_w_kernel(const float* __restrict__ fw, __bf16* __restrict__ wtp) {
  int idx = blockIdx.x*256 + threadIdx.x;
  if (idx >= CCH*CCH*49) return;
  int c = idx & 63;
  int k = (idx >> 6) & 63;
  int dydx = idx >> 12;
  wtp[((size_t)dydx*CCH + k)*CCH + c] = (__bf16)fw[((size_t)k*CCH + c)*49 + dydx];
}

// --- Kernel 3b: x (N,C,H,W) f32 -> xT (N,H*W,C) bf16 via LDS transpose ---
__global__ __launch_bounds__(256) void repack_x_kernel(const float* __restrict__ x,
                                                       __bf16* __restrict__ xT) {
  __shared__ float tile[64][65];
  int n = blockIdx.y;
  int px0 = blockIdx.x * 64;
  int tid = threadIdx.x;
  int pxl = tid & 63;
  int c0 = tid >> 6;       // 0..3
  const float* xs = x + (size_t)n*CCH*HW + px0 + pxl;
#pragma unroll
  for (int i = 0; i < 16; ++i) {
    int c = c0 + i*4;
    tile[c][pxl] = xs[(size_t)c*HW];
  }
  __syncthreads();
  int px2 = tid >> 2;            // 0..63
  int cc0 = (tid & 3) * 16;      // 0,16,32,48
  __bf16 vv[16];
#pragma unroll
  for (int j = 0; j < 16; ++j) vv[j] = (__bf16)tile[cc0 + j][px2];
  __bf16* dst = xT + ((size_t)n*HW + px0 + px2)*CCH + cc0;
  *reinterpret_cast<bf16x8*>(dst)     = *reinterpret_cast<bf16x8*>(&vv[0]);
  *reinterpret_cast<bf16x8*>(dst + 8) = *reinterpret_cast<bf16x8*>(&vv[8]);
}

// --- Kernel 4: fused warp + mask + mean over L; channel-split 4-way for TLP. ---
__global__ __launch_bounds__(256) void warp_avg_kernel(
    const __bf16* __restrict__ xT, const float* __restrict__ ptm,
    const float* __restrict__ conf_w, const float* __restrict__ tau,
    __bf16* __restrict__ pad) {
  int idx = blockIdx.x*256 + threadIdx.x;  // 0..281599
  int px = idx >> 2;
  int ch0 = (idx & 3) * 16;
  int b = (px >= HW) ? 1 : 0;
  int rem = px - b*HW;
  int h = rem / WW;
  int w = rem - h*WW;
  float acc[16];
#pragma unroll
  for (int i = 0; i < 16; ++i) acc[i] = 0.0f;
  float gy = ((float)h + 0.5f) * (float)(2.0/100.0) - 1.0f;
  float gx = ((float)w + 0.5f) * (float)(2.0/352.0) - 1.0f;
  for (int l = 0; l < LL; ++l) {
    int n = b*LL + l;
    if (l != 0 && !(conf_w[(size_t)n*HW + rem] >= tau[n])) continue;
    float th[6];
    load_theta(ptm, b, l, th);
    float sx = th[0]*gx + th[1]*gy + th[2];
    float sy = th[3]*gx + th[4]*gy + th[5];
    float fpx = (sx + 1.0f) * ((float)WW*0.5f) - 0.5f;
    float fpy = (sy + 1.0f) * ((float)HH*0.5f) - 0.5f;
    float x0 = floorf(fpx), y0 = floorf(fpy);
    float wx1 = fpx - x0, wx0 = 1.0f - wx1;
    float wy1 = fpy - y0, wy0 = 1.0f - wy1;
    float y1 = y0 + 1.0f, x1 = x0 + 1.0f;
    bool vy0 = (y0 >= 0.0f) && (y0 <= (float)(HH-1));
    bool vy1 = (y1 >= 0.0f) && (y1 <= (float)(HH-1));
    bool vx0 = (x0 >= 0.0f) && (x0 <= (float)(WW-1));
    bool vx1 = (x1 >= 0.0f) && (x1 <= (float)(WW-1));
    int yi0 = (int)fminf(fmaxf(y0, 0.0f), (float)(HH-1));
    int yi1 = (int)fminf(fmaxf(y1, 0.0f), (float)(HH-1));
    int xi0 = (int)fminf(fmaxf(x0, 0.0f), (float)(WW-1));
    int xi1 = (int)fminf(fmaxf(x1, 0.0f), (float)(WW-1));
    float wgt[4] = { wy0*wx0 * ((vy0 && vx0) ? 1.0f : 0.0f),
                     wy0*wx1 * ((vy0 && vx1) ? 1.0f : 0.0f),
                     wy1*wx0 * ((vy1 && vx0) ? 1.0f : 0.0f),
                     wy1*wx1 * ((vy1 && vx1) ? 1.0f : 0.0f) };
    int off[4] = { yi0*WW + xi0, yi0*WW + xi1, yi1*WW + xi0, yi1*WW + xi1 };
#pragma unroll
    for (int t4 = 0; t4 < 4; ++t4) {
      if (wgt[t4] == 0.0f) continue;
      float wt = wgt[t4];
      const __bf16* src = xT + ((size_t)n*HW + off[t4])*CCH + ch0;
#pragma unroll
      for (int ch = 0; ch < 2; ++ch) {
        bf16x8 v = *reinterpret_cast<const bf16x8*>(src + ch*8);
#pragma unroll
        for (int e = 0; e < 8; ++e) acc[ch*8 + e] += wt * (float)v[e];
      }
    }
  }
  __bf16* dst = pad + (((size_t)b*HP + (h+3))*WP + (w+3))*CCH + ch0;
#pragma unroll
  for (int ch = 0; ch < 2; ++ch) {
    bf16x8 o;
#pragma unroll
    for (int e = 0; e < 8; ++e) o[e] = (__bf16)(acc[ch*8 + e]*0.2f);
    *reinterpret_cast<bf16x8*>(dst + ch*8) = o;
  }
}

// --- Kernel 5: 7x7 conv implicit GEMM, forced B-pipeline + k-SPLIT for TLP. ---
// R4 post-mortem: pipeline held (VGPR 88) but pad reads are HBM-class latency
// (~600-900 cyc, cross-XCD) and the 160-cyc ring lead can't cover it; LDS 57 KB
// capped residency at 2 blocks/CU (Occupancy 13.7%). This version halves the
// k-tile per block (32 kout), halving weight LDS to 28 KB -> 4 blocks/CU, and
// doubles grid.z (kh = k-half). 2x wave interleave absorbs per-step stalls.
// B path / ring / vmcnt ledger identical to R4 (verified). New ledger:
// per dy: [7 gll][B0:4][B1:4] -> VWAIT(8) drains all 7 gll (7+8-8=7 oldest).
// Staging: chunk q=wave*7+j (0..27), dx=q>>2, qk=q&3; src row in wtp =
// dx*64 + kh*32 + qk*8 + r8; LDS row = q*8+r8 (=dx*32+qk*8+r8), row&7=r8, so
// the chunk rotation key (jcr write, cj0/cj1 read) is unchanged.

#define SBAR0() __builtin_amdgcn_sched_barrier(0)
#define VWAIT(N) do { asm volatile("s_waitcnt vmcnt(" #N ")" ::: "memory"); SBAR0(); } while(0)
#define BLOAD(dst, IMM) asm volatile("global_load_dwordx4 %0, %1, %2 offset:%c3" \
    : "=v"(dst) : "v"(voff), "s"(pad), "i"(IMM))
#define ISSUE4(SL, DX) do { BLOAD(SL[0], (DX)*128); BLOAD(SL[1], (DX)*128+64); \
    BLOAD(SL[2], (DX)*128+2048); BLOAD(SL[3], (DX)*128+2112); } while(0)
#define AFREAD(DX) do { \
  _Pragma("unroll") for (int m = 0; m < 2; ++m) { \
    af[m][0] = *(const bf16x8*)&wlds[((DX)*32 + m*16 + l16)*64 + cj0*8]; \
    af[m][1] = *(const bf16x8*)&wlds[((DX)*32 + m*16 + l16)*64 + cj1*8]; } } while(0)
#define MM(SL) do { \
  _Pragma("unroll") for (int kc = 0; kc < 2; ++kc) \
  _Pragma("unroll") for (int m = 0; m < 2; ++m) \
  _Pragma("unroll") for (int n = 0; n < 2; ++n) \
    acc[m][n] = __builtin_amdgcn_mfma_f32_16x16x32_bf16(af[m][kc], \
        *(const bf16x8*)&SL[n*2 + kc], acc[m][n], 0, 0, 0); } while(0)

__global__ __launch_bounds__(256, 4) void conv_kernel(
    const __bf16* __restrict__ pad, const __bf16* __restrict__ wtp,
    const float* __restrict__ fb, float* __restrict__ out) {
  __shared__ __bf16 wlds[7*32*64];   // [dx][k_local][c] chunk-rotated, 28672 B
  int tid = threadIdx.x;
  int wave = tid >> 6, lane = tid & 63;
  int quad = lane >> 4, l16 = lane & 15;
  int r8 = lane >> 3, jc = lane & 7;
  int jcr = (jc - r8) & 7;
  int cj0 = (quad + l16) & 7;
  int cj1 = (quad + 4 + l16) & 7;
  int bz = blockIdx.z;
  int b = bz >> 1, kh = bz & 1;      // k-half: kout in [kh*32, kh*32+32)
  int h = blockIdx.y*4 + wave;       // 0..99
  int w0 = blockIdx.x*32;            // 11*32 = 352 exact

  f32x4 acc[2][2];
#pragma unroll
  for (int m = 0; m < 2; ++m)
#pragma unroll
    for (int n = 0; n < 2; ++n) acc[m][n] = (f32x4){0.f,0.f,0.f,0.f};

  unsigned int voff = (unsigned int)((((b*HP + h)*WP + w0 + l16)*CCH)*2 + quad*16);

  int4v Bs0[4], Bs1[4], Bs2[4];
  bf16x8 af[2][2];

#pragma unroll 1
  for (int dy = 0; dy < 7; ++dy) {
    const __bf16* wdy = wtp + dy*28672;
    // barrier #1: all waves done reading previous dy's LDS
    asm volatile("s_waitcnt lgkmcnt(0)" ::: "memory"); SBAR0();
    asm volatile("s_barrier" ::: "memory"); SBAR0();
    // async stage W[dy] k-half: linear LDS dest, pre-rotated global src
#pragma unroll
    for (int j = 0; j < 7; ++j) {
      int q = wave*7 + j;            // 0..27
      int srcrow = (q >> 2)*64 + kh*32 + (q & 3)*8 + r8;
      __builtin_amdgcn_global_load_lds(
          (const __attribute__((address_space(1))) void*)(wdy + srcrow*64 + jcr*8),
          (__attribute__((address_space(3))) void*)&wlds[q*512], 16, 0, 0);
    }
    SBAR0();   // pin issue order: all 7 gll BEFORE the B-loads (vmcnt ledger)
    ISSUE4(Bs0, 0);
    ISSUE4(Bs1, 1);
    VWAIT(8);                                  // own 7 gll complete (B0,B1 in flight)
    asm volatile("s_barrier" ::: "memory"); SBAR0();   // all waves' stage visible
    AFREAD(0); ISSUE4(Bs2, 2); VWAIT(8); MM(Bs0);
    AFREAD(1); ISSUE4(Bs0, 3); VWAIT(8); MM(Bs1);
    AFREAD(2); ISSUE4(Bs1, 4); VWAIT(8); MM(Bs2);
    AFREAD(3); ISSUE4(Bs2, 5); VWAIT(8); MM(Bs0);
    AFREAD(4); ISSUE4(Bs0, 6); VWAIT(8); MM(Bs1);
    AFREAD(5);                 VWAIT(4); MM(Bs2);
    AFREAD(6);                 VWAIT(0); MM(Bs0);
    voff += WP*CCH*2;                          // advance one pad row
  }

#pragma unroll
  for (int n = 0; n < 2; ++n) {
    int wpix = w0 + n*16 + l16;
#pragma unroll
    for (int m = 0; m < 2; ++m) {
#pragma unroll
      for (int rr = 0; rr < 4; ++rr) {
        int kg = kh*32 + m*16 + quad*4 + rr;
        out[((size_t)(b*CCH + kg)*HH + h)*WW + wpix] = acc[m][n][rr] + fb[kg];
      }
    }
  }
}

extern "C" void kernel_launch(void* const* d_in, const int* in_sizes, int n_in,
                              void* d_out, int out_size, void* d_ws, size_t ws_size,
                              hipStream_t stream) {
  (void)in_sizes; (void)n_in; (void)out_size; (void)ws_size;
  const float* x   = (const float*)d_in[0];
  const float* psm = (const float*)d_in[1];
  // d_in[2] = record_len (unused by reference)
  const float* ptm = (const float*)d_in[3];
  const float* fw  = (const float*)d_in[4];
  const float* fb  = (const float*)d_in[5];
  float* out = (float*)d_out;
  char* ws = (char*)d_ws;
  float*  conf = (float*)(ws + WS_CONF);
  float*  tau  = (float*)(ws + WS_TAU);
  __bf16* wtp  = (__bf16*)(ws + WS_WTP);
  __bf16* pad  = (__bf16*)(ws + WS_PAD);
  __bf16* xT   = (__bf16*)(ws + WS_XT);

  hipMemsetAsync(pad, 0, PAD_BYTES, stream);
  conf_warp_kernel<<<dim3(3, HH, NN), 128, 0, stream>>>(psm, ptm, conf);
  pack_w_kernel<<<(CCH*CCH*49 + 255)/256, 256, 0, stream>>>(fw, wtp);
  repack_x_kernel<<<dim3(HW/64, NN), 256, 0, stream>>>(x, xT);
  topk_kernel<<<NN, 256, 0, stream>>>(conf, tau);
  warp_avg_kernel<<<dim3(NB*HW*4/256), 256, 0, stream>>>(xT, ptm, conf, tau, pad);
  conv_kernel<<<dim3(11, 25, NB*2), 256, 0, stream>>>(pad, wtp, fb, out);
}

// Round 13
// 263.097 us; speedup vs baseline: 1.3133x; 1.3133x over previous
//
#include <hip/hip_runtime.h>
#include <hip/hip_bf16.h>

#define HH 100
#define WW 352
#define NB 2
#define LL 5
#define NN 10
#define CCH 64
#define HW (HH*WW)
#define KTOP (HW/4)
#define HP (HH+6)
#define WP 390   // padded row length, covers conv reads

typedef __bf16 bf16x8 __attribute__((ext_vector_type(8)));
typedef float f32x4 __attribute__((ext_vector_type(4)));

// ws layout (bytes), 16B aligned
#define WS_CONF  0u
#define WS_TAU   1408000u
#define WS_WTP   1408064u
#define WS_PAD   1809472u
#define WS_XT    12392512u
#define PAD_BYTES ((size_t)NB*HP*WP*CCH*2)      // 10,583,040

// pad is stored GLOBALLY XOR-SWIZZLED: element (px,ch) lives at byte
//   px*128 + (((ch>>3)<<4) ^ ((px&7)<<4)) + (ch&7)*2
// i.e. the eight 16B channel-slots within each pixel's 128B block are permuted
// by px&7. Zeros are swizzle-invariant (memset ok); warp_avg writes swizzled;
// conv stages rows LINEARLY via global_load_lds (preserves swizzle) and reads
// swizzled -> every bank serves exactly 8 dwords per wave b128 read (the floor).

__device__ __forceinline__ void load_theta(const float* __restrict__ ptm, int b, int l, float th[6]) {
#pragma clang fp contract(off)
  const float* tb = ptm + ((b*LL + 0)*LL + l)*16;  // pairwise_t_matrix[b,0,l,:,:]
  th[0] = tb[0] * 1.0f;
  th[1] = tb[1] * (float)(100.0/352.0);
  th[2] = tb[3] * (float)(2.0/(2.0*0.4*352.0));
  th[3] = tb[4] * (float)(352.0/100.0);
  th[4] = tb[5] * 1.0f;
  th[5] = tb[7] * (float)(2.0/(2.0*0.4*100.0));
}

// --- Kernel 1: conf_w = bilinear-warp of sigmoid(max(psm[n,0],psm[n,1])) ---
__global__ void conf_warp_kernel(const float* __restrict__ psm,
                                 const float* __restrict__ ptm,
                                 float* __restrict__ conf_w) {
#pragma clang fp contract(off)
  int w = blockIdx.x * 128 + threadIdx.x;
  int h = blockIdx.y;
  int n = blockIdx.z;
  if (w >= WW) return;
  int b = n / LL, l = n % LL;
  float th[6];
  load_theta(ptm, b, l, th);
  float gy = ((float)h + 0.5f) * (float)(2.0/100.0) - 1.0f;
  float gx = ((float)w + 0.5f) * (float)(2.0/352.0) - 1.0f;
  float sx = th[0]*gx + th[1]*gy + th[2];
  float sy = th[3]*gx + th[4]*gy + th[5];
  float px = (sx + 1.0f) * ((float)WW * 0.5f) - 0.5f;
  float py = (sy + 1.0f) * ((float)HH * 0.5f) - 0.5f;
  float x0 = floorf(px), y0 = floorf(py);
  float wx1 = px - x0, wx0 = 1.0f - wx1;
  float wy1 = py - y0, wy0 = 1.0f - wy1;
  const float* p0 = psm + (size_t)(n*2 + 0)*HW;
  const float* p1 = psm + (size_t)(n*2 + 1)*HW;
  float yy[2] = {y0, y0 + 1.0f};
  float xx[2] = {x0, x0 + 1.0f};
  float wgt[2][2] = {{wy0*wx0, wy0*wx1}, {wy1*wx0, wy1*wx1}};
  float out = 0.0f;
  for (int iy = 0; iy < 2; ++iy) {
    for (int ix = 0; ix < 2; ++ix) {
      float yv = yy[iy], xv = xx[ix];
      float yc = fminf(fmaxf(yv, 0.0f), (float)(HH-1));
      float xc = fminf(fmaxf(xv, 0.0f), (float)(WW-1));
      int yi = (int)yc, xi = (int)xc;
      int idx = yi*WW + xi;
      float m = fmaxf(p0[idx], p1[idx]);
      float v = 1.0f / (1.0f + expf(-m));
      bool valid = (yv >= 0.0f) && (yv <= (float)(HH-1)) && (xv >= 0.0f) && (xv <= (float)(WW-1));
      out += (valid ? v : 0.0f) * wgt[iy][ix];
    }
  }
  conf_w[(size_t)n*HW + h*WW + w] = out;
}

// inclusive block scan over 256 threads (thread order = descending bins)
__device__ __forceinline__ unsigned int scan_incl(unsigned int v, int lane, int wid,
                                                  volatile unsigned int* wsum) {
  unsigned int inc = v;
  for (int off = 1; off < 64; off <<= 1) {
    unsigned int o = __shfl_up(inc, off);
    if (lane >= off) inc += o;
  }
  if (lane == 63) wsum[wid] = inc;
  __syncthreads();
  unsigned int wadd = 0;
  for (int w2 = 0; w2 < wid; ++w2) wadd += wsum[w2];
  return inc + wadd;
}

// --- Kernel 2: exact K-th largest per image, 3-round (14/14/4-bit) LDS radix select ---
__global__ __launch_bounds__(256) void topk_kernel(const float* __restrict__ conf_w,
                                                   float* __restrict__ tau) {
  __shared__ unsigned int hist[16384];
  __shared__ unsigned int wsum[4];
  __shared__ unsigned int s_pref, s_mask, s_k;
  int n = blockIdx.x;
  int tid = threadIdx.x, lane = tid & 63, wid = tid >> 6;
  const float4* src = (const float4*)(conf_w + (size_t)n*HW);
  if (tid == 0) { s_pref = 0u; s_mask = 0u; s_k = KTOP; }
  __syncthreads();
  const int shifts[3] = {18, 4, 0};
  const int widths[3] = {14, 14, 4};
  for (int r = 0; r < 3; ++r) {
    int shift = shifts[r];
    int nbins = 1 << widths[r];
    unsigned int fmask = (unsigned int)(nbins - 1);
    for (int i = tid; i < nbins; i += 256) hist[i] = 0u;
    __syncthreads();
    unsigned int maskhi = s_mask, pref = s_pref, k = s_k;
    for (int i = tid; i < HW/4; i += 256) {
      float4 v = src[i];
      unsigned int u0 = __float_as_uint(v.x);
      unsigned int u1 = __float_as_uint(v.y);
      unsigned int u2 = __float_as_uint(v.z);
      unsigned int u3 = __float_as_uint(v.w);
      if ((u0 & maskhi) == pref) atomicAdd(&hist[(u0 >> shift) & fmask], 1u);
      if ((u1 & maskhi) == pref) atomicAdd(&hist[(u1 >> shift) & fmask], 1u);
      if ((u2 & maskhi) == pref) atomicAdd(&hist[(u2 >> shift) & fmask], 1u);
      if ((u3 & maskhi) == pref) atomicAdd(&hist[(u3 >> shift) & fmask], 1u);
    }
    __syncthreads();
    int C = nbins >> 8; if (C == 0) C = 1;
    int active = (C * 256 > nbins) ? nbins : 256;
    int top = nbins - 1 - tid*C;
    unsigned int csum = 0u;
    if (tid < active)
      for (int i = 0; i < C; ++i) csum += hist[top - i];
    unsigned int incl = scan_incl(csum, lane, wid, wsum);
    unsigned int excl = incl - csum;
    if (tid < active && excl < k && incl >= k) {
      unsigned int run = excl;
      for (int i = 0; i < C; ++i) {
        unsigned int c = hist[top - i];
        if (run + c >= k) {
          unsigned int bin = (unsigned int)(top - i);
          s_pref = pref | (bin << shift);
          s_mask = maskhi | (fmask << shift);
          s_k = k - run;
          break;
        }
        run += c;
      }
    }
    __syncthreads();
  }
  if (tid == 0) tau[n] = __uint_as_float(s_pref);
}

// --- Kernel 3: weights fuse_w[k][c][dy][dx] -> wtp[(dy*7+dx)*64 + k][c] bf16 ---
__global__ void pack_w_kernel(const float* __restrict__ fw, __bf16* __restrict__ wtp) {
  int idx = blockIdx.x*256 + threadIdx.x;
  if (idx >= CCH*CCH*49) return;
  int c = idx & 63;
  int k = (idx >> 6) & 63;
  int dydx = idx >> 12;
  wtp[((size_t)dydx*CCH + k)*CCH + c] = (__bf16)fw[((size_t)k*CCH + c)*49 + dydx];
}

// --- Kernel 3b: x (N,C,H,W) f32 -> xT (N,H*W,C) bf16 via LDS transpose ---
__global__ __launch_bounds__(256) void repack_x_kernel(const float* __restrict__ x,
                                                       __bf16* __restrict__ xT) {
  __shared__ float tile[64][65];
  int n = blockIdx.y;
  int px0 = blockIdx.x * 64;
  int tid = threadIdx.x;
  int pxl = tid & 63;
  int c0 = tid >> 6;       // 0..3
  const float* xs = x + (size_t)n*CCH*HW + px0 + pxl;
#pragma unroll
  for (int i = 0; i < 16; ++i) {
    int c = c0 + i*4;
    tile[c][pxl] = xs[(size_t)c*HW];
  }
  __syncthreads();
  int px2 = tid >> 2;            // 0..63
  int cc0 = (tid & 3) * 16;      // 0,16,32,48
  __bf16 vv[16];
#pragma unroll
  for (int j = 0; j < 16; ++j) vv[j] = (__bf16)tile[cc0 + j][px2];
  __bf16* dst = xT + ((size_t)n*HW + px0 + px2)*CCH + cc0;
  *reinterpret_cast<bf16x8*>(dst)     = *reinterpret_cast<bf16x8*>(&vv[0]);
  *reinterpret_cast<bf16x8*>(dst + 8) = *reinterpret_cast<bf16x8*>(&vv[8]);
}

// --- Kernel 4: fused warp + mask + mean over L; channel-split 4-way for TLP. ---
// Writes pad with the global XOR swizzle (see top comment).
__global__ __launch_bounds__(256) void warp_avg_kernel(
    const __bf16* __restrict__ xT, const float* __restrict__ ptm,
    const float* __restrict__ conf_w, const float* __restrict__ tau,
    __bf16* __restrict__ pad) {
  int idx = blockIdx.x*256 + threadIdx.x;  // 0..281599
  int px = idx >> 2;
  int ch0 = (idx & 3) * 16;
  int b = (px >= HW) ? 1 : 0;
  int rem = px - b*HW;
  int h = rem / WW;
  int w = rem - h*WW;
  float acc[16];
#pragma unroll
  for (int i = 0; i < 16; ++i) acc[i] = 0.0f;
  float gy = ((float)h + 0.5f) * (float)(2.0/100.0) - 1.0f;
  float gx = ((float)w + 0.5f) * (float)(2.0/352.0) - 1.0f;
  for (int l = 0; l < LL; ++l) {
    int n = b*LL + l;
    if (l != 0 && !(conf_w[(size_t)n*HW + rem] >= tau[n])) continue;
    float th[6];
    load_theta(ptm, b, l, th);
    float sx = th[0]*gx + th[1]*gy + th[2];
    float sy = th[3]*gx + th[4]*gy + th[5];
    float fpx = (sx + 1.0f) * ((float)WW*0.5f) - 0.5f;
    float fpy = (sy + 1.0f) * ((float)HH*0.5f) - 0.5f;
    float x0 = floorf(fpx), y0 = floorf(fpy);
    float wx1 = fpx - x0, wx0 = 1.0f - wx1;
    float wy1 = fpy - y0, wy0 = 1.0f - wy1;
    float y1 = y0 + 1.0f, x1 = x0 + 1.0f;
    bool vy0 = (y0 >= 0.0f) && (y0 <= (float)(HH-1));
    bool vy1 = (y1 >= 0.0f) && (y1 <= (float)(HH-1));
    bool vx0 = (x0 >= 0.0f) && (x0 <= (float)(WW-1));
    bool vx1 = (x1 >= 0.0f) && (x1 <= (float)(WW-1));
    int yi0 = (int)fminf(fmaxf(y0, 0.0f), (float)(HH-1));
    int yi1 = (int)fminf(fmaxf(y1, 0.0f), (float)(HH-1));
    int xi0 = (int)fminf(fmaxf(x0, 0.0f), (float)(WW-1));
    int xi1 = (int)fminf(fmaxf(x1, 0.0f), (float)(WW-1));
    float wgt[4] = { wy0*wx0 * ((vy0 && vx0) ? 1.0f : 0.0f),
                     wy0*wx1 * ((vy0 && vx1) ? 1.0f : 0.0f),
                     wy1*wx0 * ((vy1 && vx0) ? 1.0f : 0.0f),
                     wy1*wx1 * ((vy1 && vx1) ? 1.0f : 0.0f) };
    int off[4] = { yi0*WW + xi0, yi0*WW + xi1, yi1*WW + xi0, yi1*WW + xi1 };
#pragma unroll
    for (int t4 = 0; t4 < 4; ++t4) {
      if (wgt[t4] == 0.0f) continue;
      float wt = wgt[t4];
      const __bf16* src = xT + ((size_t)n*HW + off[t4])*CCH + ch0;
#pragma unroll
      for (int ch = 0; ch < 2; ++ch) {
        bf16x8 v = *reinterpret_cast<const bf16x8*>(src + ch*8);
#pragma unroll
        for (int e = 0; e < 8; ++e) acc[ch*8 + e] += wt * (float)v[e];
      }
    }
  }
  // swizzled store: pixel (h+3, w+3), channels ch0..ch0+15 as two 16B slots
  char* rowb = (char*)pad + (size_t)((b*HP + (h+3))*WP)*128;
  int px_p = w + 3;
  int key = (px_p & 7) << 4;
#pragma unroll
  for (int ch = 0; ch < 2; ++ch) {
    bf16x8 o;
#pragma unroll
    for (int e = 0; e < 8; ++e) o[e] = (__bf16)(acc[ch*8 + e]*0.2f);
    int slotb = (ch0*2 + ch*16) ^ key;     // 16B-aligned, bits 4-6 permuted
    *reinterpret_cast<bf16x8*>(rowb + (size_t)px_p*128 + slotb) = o;
  }
}

// --- Kernel 5: 7x7 conv implicit GEMM, ALL operands from LDS (no vmem in dx loop). ---
// R7 post-mortem: per-step global B-loads are a serialized vmem path (~3900
// cyc/step, 10x latency+BW floors); doubling TLP made it worse. This version
// stages BOTH operands per dy: wlds = weight k-half slice (28.7 KB, R7's
// HW-verified k-split staging+rotation), plds = one pad row per wave (4 x 9216 B,
// linear gll copy of the globally-swizzled pad). Inner dx loop = 12 ds_read_b128
// + 16 MFMA per wave, compiler-scheduled lgkmcnt (m97 regime). LDS = 65536 B
// exactly -> 2 blocks/CU; one block's staging overlaps the other's compute.
// Block: 4 waves x (4 rows, 64 px, 32 kout). Grid (6, 25, NB*2).

#define AFREAD(DX) do { \
  _Pragma("unroll") for (int m = 0; m < 2; ++m) { \
    af[m][0] = *(const bf16x8*)&wlds[((DX)*32 + m*16 + l16)*64 + cj0*8]; \
    af[m][1] = *(const bf16x8*)&wlds[((DX)*32 + m*16 + l16)*64 + cj1*8]; } } while(0)

__global__ __launch_bounds__(256, 2) void conv_kernel(
    const __bf16* __restrict__ pad, const __bf16* __restrict__ wtp,
    const float* __restrict__ fb, float* __restrict__ out) {
  __shared__ __bf16 wlds[7*32*64];   // [dx][k_local][c] chunk-rotated, 28672 B
  __shared__ __bf16 plds[4][4608];   // one swizzled pad row per wave, 36864 B
  int tid = threadIdx.x;
  int wave = tid >> 6, lane = tid & 63;
  int quad = lane >> 4, l16 = lane & 15;
  int r8 = lane >> 3, jc = lane & 7;
  int jcr = (jc - r8) & 7;
  int cj0 = (quad + l16) & 7;
  int cj1 = (quad + 4 + l16) & 7;
  int bz = blockIdx.z;
  int b = bz >> 1, kh = bz & 1;      // k-half: kout in [kh*32, kh*32+32)
  int h0 = blockIdx.y*4;
  int h = h0 + wave;                 // this wave's output row, 0..99
  int w0 = blockIdx.x*64;            // 6 tiles; last tile masked at store

  f32x4 acc[2][4];
#pragma unroll
  for (int m = 0; m < 2; ++m)
#pragma unroll
    for (int n = 0; n < 4; ++n) acc[m][n] = (f32x4){0.f,0.f,0.f,0.f};

  bf16x8 af[2][2];

#pragma unroll 1
  for (int dy = 0; dy < 7; ++dy) {
    __syncthreads();   // all waves done reading wlds/plds of previous dy
    // stage weight slice k-half (R7 HW-verified algebra)
    const __bf16* wdy = wtp + dy*28672;
#pragma unroll
    for (int j = 0; j < 7; ++j) {
      int q = wave*7 + j;            // 0..27
      int srcrow = (q >> 2)*64 + kh*32 + (q & 3)*8 + r8;
      __builtin_amdgcn_global_load_lds(
          (const __attribute__((address_space(1))) void*)(wdy + srcrow*64 + jcr*8),
          (__attribute__((address_space(3))) void*)&wlds[q*512], 16, 0, 0);
    }
    // stage this wave's pad row (linear copy preserves global swizzle)
    const __bf16* prow_g = pad + (size_t)((b*HP + h + dy)*WP + w0)*CCH;
#pragma unroll
    for (int j = 0; j < 9; ++j) {
      __builtin_amdgcn_global_load_lds(
          (const __attribute__((address_space(1))) void*)(prow_g + j*512 + lane*8),
          (__attribute__((address_space(3))) void*)&plds[wave][j*512], 16, 0, 0);
    }
    __syncthreads();   // drains vmcnt -> staged LDS visible to all
#pragma unroll
    for (int dx = 0; dx < 7; ++dx) {
      AFREAD(dx);
      bf16x8 bf[4][2];
#pragma unroll
      for (int n = 0; n < 4; ++n) {
        int p = dx + n*16 + l16;               // local px in [0,70)
        int key = (p & 7) << 4;
#pragma unroll
        for (int kc = 0; kc < 2; ++kc) {
          int slotb = ((quad + 4*kc) << 4) ^ key;
          bf[n][kc] = *(const bf16x8*)((const char*)&plds[wave][0] + p*128 + slotb);
        }
      }
#pragma unroll
      for (int kc = 0; kc < 2; ++kc)
#pragma unroll
        for (int m = 0; m < 2; ++m)
#pragma unroll
          for (int n = 0; n < 4; ++n)
            acc[m][n] = __builtin_amdgcn_mfma_f32_16x16x32_bf16(af[m][kc], bf[n][kc], acc[m][n], 0, 0, 0);
    }
  }

#pragma unroll
  for (int n = 0; n < 4; ++n) {
    int wpix = w0 + n*16 + l16;
    if (wpix < WW) {
#pragma unroll
      for (int m = 0; m < 2; ++m) {
#pragma unroll
        for (int rr = 0; rr < 4; ++rr) {
          int kg = kh*32 + m*16 + quad*4 + rr;
          out[((size_t)(b*CCH + kg)*HH + h)*WW + wpix] = acc[m][n][rr] + fb[kg];
        }
      }
    }
  }
}

extern "C" void kernel_launch(void* const* d_in, const int* in_sizes, int n_in,
                              void* d_out, int out_size, void* d_ws, size_t ws_size,
                              hipStream_t stream) {
  (void)in_sizes; (void)n_in; (void)out_size; (void)ws_size;
  const float* x   = (const float*)d_in[0];
  const float* psm = (const float*)d_in[1];
  // d_in[2] = record_len (unused by reference)
  const float* ptm = (const float*)d_in[3];
  const float* fw  = (const float*)d_in[4];
  const float* fb  = (const float*)d_in[5];
  float* out = (float*)d_out;
  char* ws = (char*)d_ws;
  float*  conf = (float*)(ws + WS_CONF);
  float*  tau  = (float*)(ws + WS_TAU);
  __bf16* wtp  = (__bf16*)(ws + WS_WTP);
  __bf16* pad  = (__bf16*)(ws + WS_PAD);
  __bf16* xT   = (__bf16*)(ws + WS_XT);

  hipMemsetAsync(pad, 0, PAD_BYTES, stream);
  conf_warp_kernel<<<dim3(3, HH, NN), 128, 0, stream>>>(psm, ptm, conf);
  pack_w_kernel<<<(CCH*CCH*49 + 255)/256, 256, 0, stream>>>(fw, wtp);
  repack_x_kernel<<<dim3(HW/64, NN), 256, 0, stream>>>(x, xT);
  topk_kernel<<<NN, 256, 0, stream>>>(conf, tau);
  warp_avg_kernel<<<dim3(NB*HW*4/256), 256, 0, stream>>>(xT, ptm, conf, tau, pad);
  conv_kernel<<<dim3(6, 25, NB*2), 256, 0, stream>>>(pad, wtp, fb, out);
}